// Round 5
// baseline (23413.474 us; speedup 1.0000x reference)
//
#include <hip/hip_runtime.h>

#define H     512
#define BQ    64
#define TT    512
#define CIN   64
#define COUT  64
#define NWG   132           // 64 stage-A + 64 stage-B + 4 FC
#define THREADS 256
#define RD    4             // ring depth (slots)

typedef unsigned int  uint;
typedef unsigned short ushort;
typedef unsigned long long u64;
typedef short bf16x8 __attribute__((ext_vector_type(8)));
typedef float f32x4  __attribute__((ext_vector_type(4)));

// LDS layout (bytes): gate-interleaved weight pair-tiles, bf16 hi+lo
#define GH_BASE   0          // 2 tiles K=512 : 64 KB
#define GI_BASE   65536      // 2 tiles K<=512: 64 KB
#define GI0_BASE  131072     // 2 tiles K=64  :  8 KB  (dec-A t=0 only)
#define SMEM_SIZE 139264

// ws layout (bytes)
#define WS_FA     0          // uint[64] ready-flags stage A (1 step = 1 count)
#define WS_FB     1024       // uint[64] stage B
#define WS_FF     2048       // uint[4]  FC
#define WS_GFLAGS 4096       // legacy grid-barrier flags (prepass only), 132*64B
#define WS_BAR_SZ 16384
#define WS_BP     16384      // b' f32[1536]
#define WS_F0H    22528      // f0 hi bf16[64][64]
#define WS_F0L    30720
#define WS_H0RH   40960      // h0 ring [4][64][512] bf16 hi
#define WS_H0RL   303104
#define WS_H1RH   565248
#define WS_H1RL   827392
#define WS_M      1089536    // M f32[1536][512]  (ends 4235264)

struct Params {
  const float *x, *f0;
  const float *eWih0,*eWhh0,*ebih0,*ebhh0,*eWih1,*eWhh1,*ebih1,*ebhh1;
  const float *dWih0,*dWhh0,*dbih0,*dbhh0,*dWih1,*dWhh1,*dbih1,*dbhh1;
  const float *fcW,*fcb;
  float* out;
  char* ws;
};

__device__ __forceinline__ ushort f2bf(float v){
  uint b = __float_as_uint(v);
  return (ushort)((b + 0x7FFFu + ((b >> 16) & 1u)) >> 16);
}
__device__ __forceinline__ float bf2f(ushort u){ return __uint_as_float(((uint)u) << 16); }

// ---------------- dataflow sync: monotonic ready-flags, relaxed agent atomics.
// All 64 lanes of every wave poll one flag each (64 flags = 4 cache lines, one
// vector load per iteration). R4 validated this coherence scheme (no fences
// needed: write-through stores + coherence-point loads).
__device__ __forceinline__ void waitge(const uint* __restrict__ f, uint thr, int l){
  uint it = 0;
  while (!__all((int)(__hip_atomic_load(&f[l], __ATOMIC_RELAXED, __HIP_MEMORY_SCOPE_AGENT) >= thr))){
    __builtin_amdgcn_s_sleep(1);
    if ((++it & 63u) == 0u) __builtin_amdgcn_fence(__ATOMIC_ACQUIRE, "agent");  // stale-spin safety only
  }
  asm volatile("" ::: "memory");
}
__device__ __forceinline__ void waitgeF(const uint* __restrict__ f, uint thr, int l){
  uint it = 0;
  while (!__all(l < 4 ? (int)(__hip_atomic_load(&f[l], __ATOMIC_RELAXED, __HIP_MEMORY_SCOPE_AGENT) >= thr) : 1)){
    __builtin_amdgcn_s_sleep(1);
    if ((++it & 63u) == 0u) __builtin_amdgcn_fence(__ATOMIC_ACQUIRE, "agent");
  }
  asm volatile("" ::: "memory");
}
// publish: call from tid==0 AFTER __syncthreads (vmcnt drain orders ring stores first)
__device__ __forceinline__ void publish(uint* f, uint v){
  __hip_atomic_store(f, v, __ATOMIC_RELAXED, __HIP_MEMORY_SCOPE_AGENT);
}

// ---------------- legacy grid barrier (prepass only)
__device__ __forceinline__ void gbar(uint* flags, uint r, int wg, int tid){
  __syncthreads();
  if (tid == 0){
    __builtin_amdgcn_fence(__ATOMIC_RELEASE, "agent");   // flush plain-stored staging
    __hip_atomic_store(&flags[wg*16], r, __ATOMIC_RELAXED, __HIP_MEMORY_SCOPE_AGENT);
  }
  asm volatile("" ::: "memory");
  if (tid < NWG){
    uint it = 0;
    while (__hip_atomic_load(&flags[tid*16], __ATOMIC_RELAXED, __HIP_MEMORY_SCOPE_AGENT) < r){
      __builtin_amdgcn_s_sleep(1);
      if ((++it & 15u) == 0u) __builtin_amdgcn_fence(__ATOMIC_ACQUIRE, "agent");
    }
  }
  __syncthreads();
  __builtin_amdgcn_fence(__ATOMIC_ACQUIRE, "agent");     // invalidate stale cached lines once
}

// ---------------- pack 2 gate-interleaved pair-tiles (32 slots x K) into LDS
template<int K>
__device__ void packW(char* lds, int base, const float* __restrict__ W, int colbase, int tid){
  for (int e = tid; e < 32*K; e += THREADS){
    int S = e / K, k = e - S*K;
    int gate = S & 3, hcl = S >> 2;
    float v = (gate < 3) ? W[(gate*H + colbase + hcl)*K + k] : 0.f;
    ushort hi = f2bf(v);
    ushort lo = f2bf(v - bf2f(hi));
    int tau = S >> 4, s = S & 15;
    int off = ((s*K + k)*2) ^ ((s & 7) << 4);
    char* tb = lds + base + tau*(16*K*4);
    *(ushort*)(tb + off) = hi;
    *(ushort*)(tb + 16*K*2 + off) = lo;
  }
}

__device__ void packFC(char* lds, const float* __restrict__ fcW, int colbase, int tid){
  for (int e = tid; e < 16*512; e += THREADS){
    int s = e >> 9, k = e & 511;
    float v = fcW[(colbase + s)*512 + k];
    ushort hi = f2bf(v);
    ushort lo = f2bf(v - bf2f(hi));
    int off = ((s*512 + k)*2) ^ ((s & 7) << 4);
    *(ushort*)(lds + off) = hi;
    *(ushort*)(lds + 16*512*2 + off) = lo;
  }
}

__device__ __forceinline__ void loadBias(const float* __restrict__ src, int colbase, int c, float* b){
#pragma unroll
  for (int tau = 0; tau < 2; ++tau){
    int gate = c & 3, hcl = 4*tau + (c >> 2);
    b[tau] = (gate < 3) ? src[gate*H + colbase + hcl] : 0.f;
  }
}

// ---------------- 64xNTAU*16 GEMM tile, split-bf16 3-term, weights from LDS
template<int NTAU, int K, bool COH>
__device__ __forceinline__ void gemm(const ushort* __restrict__ AH, const ushort* __restrict__ AL,
                                     const char* lds, int base, const float* bias,
                                     int m, int lane, f32x4* pre){
  const int c = lane & 15, g = lane >> 4;
  const int rowoff = (m*16 + c)*K + g*8;
  constexpr int NK = K/32;
  bf16x8 ahv[NK], alv[NK];
#pragma unroll
  for (int kc = 0; kc < NK; ++kc){
    if (COH){
      union { u64 q[2]; bf16x8 v; } ua, ub;
      const u64* pa = (const u64*)(AH + rowoff + kc*32);
      const u64* pb = (const u64*)(AL + rowoff + kc*32);
      ua.q[0] = __hip_atomic_load(pa + 0, __ATOMIC_RELAXED, __HIP_MEMORY_SCOPE_AGENT);
      ua.q[1] = __hip_atomic_load(pa + 1, __ATOMIC_RELAXED, __HIP_MEMORY_SCOPE_AGENT);
      ub.q[0] = __hip_atomic_load(pb + 0, __ATOMIC_RELAXED, __HIP_MEMORY_SCOPE_AGENT);
      ub.q[1] = __hip_atomic_load(pb + 1, __ATOMIC_RELAXED, __HIP_MEMORY_SCOPE_AGENT);
      ahv[kc] = ua.v; alv[kc] = ub.v;
    } else {
      ahv[kc] = *(const bf16x8*)(AH + rowoff + kc*32);
      alv[kc] = *(const bf16x8*)(AL + rowoff + kc*32);
    }
  }
  f32x4 a1[NTAU], a2[NTAU];
#pragma unroll
  for (int tau = 0; tau < NTAU; ++tau){
    a1[tau] = f32x4{bias[tau], bias[tau], bias[tau], bias[tau]};
    a2[tau] = f32x4{0.f, 0.f, 0.f, 0.f};
  }
#pragma unroll
  for (int kc = 0; kc < NK; ++kc){
    const int off = ((c*K + kc*32 + g*8)*2) ^ ((c & 7) << 4);
#pragma unroll
    for (int tau = 0; tau < NTAU; ++tau){
      const char* tb = lds + base + tau*(16*K*4);
      bf16x8 wh = *(const bf16x8*)(tb + off);
      bf16x8 wl = *(const bf16x8*)(tb + 16*K*2 + off);
      a1[tau] = __builtin_amdgcn_mfma_f32_16x16x32_bf16(ahv[kc], wh, a1[tau], 0, 0, 0);
      a2[tau] = __builtin_amdgcn_mfma_f32_16x16x32_bf16(ahv[kc], wl, a2[tau], 0, 0, 0);
      a2[tau] = __builtin_amdgcn_mfma_f32_16x16x32_bf16(alv[kc], wh, a2[tau], 0, 0, 0);
    }
  }
#pragma unroll
  for (int tau = 0; tau < NTAU; ++tau) pre[tau] = a1[tau] + a2[tau];
}

// ---------------- GRU gates + hidden store (write-through relaxed agent atomics)
__device__ __forceinline__ void gates_store(const f32x4* pgi, const f32x4* pgh, f32x4* hold,
                                            ushort* __restrict__ outH, ushort* __restrict__ outL,
                                            int colb, int m, int lane){
  const int c = lane & 15, g = lane >> 4;
#pragma unroll
  for (int tau = 0; tau < 2; ++tau){
    f32x4 s, n, hn, rsh, zsh;
#pragma unroll
    for (int q = 0; q < 4; ++q) s[q] = 1.f / (1.f + expf(-(pgi[tau][q] + pgh[tau][q])));
#pragma unroll
    for (int q = 0; q < 4; ++q) rsh[q] = __shfl_xor(s[q], 2, 64);
#pragma unroll
    for (int q = 0; q < 4; ++q) zsh[q] = __shfl_xor(s[q], 3, 64);
#pragma unroll
    for (int q = 0; q < 4; ++q) n[q] = tanhf(pgi[tau][q] + rsh[q]*pgh[tau][q]);
#pragma unroll
    for (int q = 0; q < 4; ++q) hn[q] = (1.f - zsh[q])*n[q] + zsh[q]*hold[tau][q];
    hold[tau] = hn;
    if ((c & 3) == 2){
      const int col = colb + 4*tau + (c >> 2);
#pragma unroll
      for (int q = 0; q < 4; ++q){
        const int row = m*16 + g*4 + q;
        ushort hi = f2bf(hn[q]);
        ushort lo = f2bf(hn[q] - bf2f(hi));
        __hip_atomic_store(&outH[row*H + col], hi, __ATOMIC_RELAXED, __HIP_MEMORY_SCOPE_AGENT);
        __hip_atomic_store(&outL[row*H + col], lo, __ATOMIC_RELAXED, __HIP_MEMORY_SCOPE_AGENT);
      }
    }
  }
}

__device__ __forceinline__ f32x4 bc4(float v){ return f32x4{v, v, v, v}; }

__global__ __launch_bounds__(THREADS, 1) void rnn_persist(Params p){
  extern __shared__ char smem[];
  char* ws = p.ws;
  uint* fA     = (uint*)(ws + WS_FA);
  uint* fB     = (uint*)(ws + WS_FB);
  uint* fF     = (uint*)(ws + WS_FF);
  uint* gflags = (uint*)(ws + WS_GFLAGS);
  float*  bp   = (float*)(ws + WS_BP);
  ushort* f0H  = (ushort*)(ws + WS_F0H);
  ushort* f0L  = (ushort*)(ws + WS_F0L);
  ushort* h0rH = (ushort*)(ws + WS_H0RH);
  ushort* h0rL = (ushort*)(ws + WS_H0RL);
  ushort* h1rH = (ushort*)(ws + WS_H1RH);
  ushort* h1rL = (ushort*)(ws + WS_H1RL);
  float*  Mw   = (float*)(ws + WS_M);
  ushort* xTH  = (ushort*)(void*)p.out;              // staged in d_out; dead before FC writes begin
  ushort* xTL  = xTH + TT*BQ*CIN;

  const int wg = blockIdx.x, tid = threadIdx.x;
  const int wid = tid >> 6, lane = tid & 63;
  const int c = lane & 15;
  const int l = lane;                                 // flag-poll lane
  const int gtid = wg*THREADS + tid;
  const int gstride = NWG*THREADS;

  // ================= prepass: xT (transpose+split), f0, M = dWih0@fcW, b'
  for (int e = gtid; e < TT*BQ*CIN; e += gstride){
    int t = e >> 12, b = (e >> 6) & 63, cc = e & 63;
    float v = p.x[(b*CIN + cc)*TT + t];
    ushort hi = f2bf(v);
    xTH[e] = hi; xTL[e] = f2bf(v - bf2f(hi));
  }
  for (int e = gtid; e < BQ*COUT; e += gstride){
    float v = p.f0[e];
    ushort hi = f2bf(v);
    f0H[e] = hi; f0L[e] = f2bf(v - bf2f(hi));
  }
  {
    const int total = 1536*512;
    const int per = (total + gstride - 1) / gstride;
    const int start = gtid * per;
    for (int i = 0; i < per; ++i){
      int e = start + i;
      if (e >= total) break;
      int rr = e >> 9, q = e & 511;
      float acc = 0.f;
      for (int k = 0; k < 64; ++k) acc += p.dWih0[rr*64 + k] * p.fcW[k*512 + q];
      Mw[e] = acc;
    }
  }
  for (int e = gtid; e < 1536; e += gstride){
    float acc = p.dbih0[e];
    for (int k = 0; k < 64; ++k) acc += p.dWih0[e*64 + k] * p.fcb[k];
    bp[e] = acc;
  }
  gbar(gflags, 1, wg, tid);   // the ONLY grid barrier

  const bool isA = (wg < 64), isB = (wg >= 64 && wg < 128);
  const int colb = isA ? wg*8 : (wg - 64)*8;
  float bgi[2] = {0.f,0.f}, bgh[2] = {0.f,0.f}, bgi0[2] = {0.f,0.f}, bfc = 0.f;
  f32x4 hold[2]; hold[0] = bc4(0.f); hold[1] = bc4(0.f);

  if (isA){
    // ---- encoder L0: barrier-free recurrent chain; B trails via flags (D=4 slack)
    packW<64 >(smem, GI_BASE, p.eWih0, colb, tid);
    packW<512>(smem, GH_BASE, p.eWhh0, colb, tid);
    loadBias(p.ebih0, colb, c, bgi); loadBias(p.ebhh0, colb, c, bgh);
    __syncthreads();
    for (int t = 0; t < TT; ++t){
      f32x4 pgi[2], pgh[2];
      if (t > 0){
        waitge(fA, (uint)t, l);                               // h0^{t-1} ready (all A)
        gemm<2,512,true>(h0rH + ((t-1)&3)*32768, h0rL + ((t-1)&3)*32768, smem, GH_BASE, bgh, wid, lane, pgh);
      } else { pgh[0] = bc4(bgh[0]); pgh[1] = bc4(bgh[1]); }
      gemm<2,64,false>(xTH + t*4096, xTL + t*4096, smem, GI_BASE, bgi, wid, lane, pgi);
      if (t >= RD) waitge(fB, (uint)(t-RD+1), l);             // overwrite guard: B consumed h0^{t-RD}
      gates_store(pgi, pgh, hold, h0rH + (t&3)*32768, h0rL + (t&3)*32768, colb, wid, lane);
      __syncthreads();
      if (tid == 0) publish(&fA[wg], (uint)(t+1));
    }
    // ---- repack for decoder L0 (LDS private; no grid sync needed)
    __syncthreads();
    packW<512>(smem, GH_BASE, p.dWhh0, colb, tid);
    packW<512>(smem, GI_BASE, Mw,      colb, tid);            // folded FC->L0 input weights
    packW<64 >(smem, GI0_BASE, p.dWih0, colb, tid);
    loadBias(bp,      colb, c, bgi);
    loadBias(p.dbhh0, colb, c, bgh);
    loadBias(p.dbih0, colb, c, bgi0);
    __syncthreads();
    // hold carries enc-final h0 in registers
    for (int t = 0; t < TT; ++t){
      const int g = 512 + t;
      f32x4 pgi[2], pgh[2];
      waitge(fA, (uint)g, l);                                  // h0^{g-1} (own group, early)
      gemm<2,512,true>(h0rH + ((g-1)&3)*32768, h0rL + ((g-1)&3)*32768, smem, GH_BASE, bgh, wid, lane, pgh);
      waitge(fB, (uint)g, l);                                  // h1^{g-1} + overwrite guard
      if (t == 0)
        gemm<2,64,false>(f0H, f0L, smem, GI0_BASE, bgi0, wid, lane, pgi);
      else
        gemm<2,512,true>(h1rH + ((g-1)&3)*32768, h1rL + ((g-1)&3)*32768, smem, GI_BASE, bgi, wid, lane, pgi);
      gates_store(pgi, pgh, hold, h0rH + (g&3)*32768, h0rL + (g&3)*32768, colb, wid, lane);
      __syncthreads();
      if (tid == 0) publish(&fA[wg], (uint)(g+1));
    }
  } else if (isB){
    // ---- encoder L1: consumes A's ring
    packW<512>(smem, GI_BASE, p.eWih1, colb, tid);
    packW<512>(smem, GH_BASE, p.eWhh1, colb, tid);
    loadBias(p.ebih1, colb, c, bgi); loadBias(p.ebhh1, colb, c, bgh);
    __syncthreads();
    for (int t = 0; t < TT; ++t){
      f32x4 pgi[2], pgh[2];
      if (t > 0){
        waitge(fB, (uint)t, l);                               // h1^{t-1} (own group)
        gemm<2,512,true>(h1rH + ((t-1)&3)*32768, h1rL + ((t-1)&3)*32768, smem, GH_BASE, bgh, wid, lane, pgh);
      } else { pgh[0] = bc4(bgh[0]); pgh[1] = bc4(bgh[1]); }
      waitge(fA, (uint)(t+1), l);                             // h0^t ready
      gemm<2,512,true>(h0rH + (t&3)*32768, h0rL + (t&3)*32768, smem, GI_BASE, bgi, wid, lane, pgi);
      gates_store(pgi, pgh, hold, h1rH + (t&3)*32768, h1rL + (t&3)*32768, colb, wid, lane);
      __syncthreads();
      if (tid == 0) publish(&fB[wg-64], (uint)(t+1));
    }
    // ---- repack for decoder L1
    __syncthreads();
    packW<512>(smem, GI_BASE, p.dWih1, colb, tid);
    packW<512>(smem, GH_BASE, p.dWhh1, colb, tid);
    loadBias(p.dbih1, colb, c, bgi); loadBias(p.dbhh1, colb, c, bgh);
    __syncthreads();
    for (int t = 0; t < TT; ++t){
      const int g = 512 + t;
      f32x4 pgi[2], pgh[2];
      waitge(fB, (uint)g, l);                                  // h1^{g-1} (own group, early)
      gemm<2,512,true>(h1rH + ((g-1)&3)*32768, h1rL + ((g-1)&3)*32768, smem, GH_BASE, bgh, wid, lane, pgh);
      if (t >= RD) waitgeF(fF, (uint)(g - RD + 1 + 1), l);     // FC consumed h1^{g-RD} (fF = 513+t' after out_{t'})
      waitge(fA, (uint)(g+1), l);                              // h0^g ready
      gemm<2,512,true>(h0rH + (g&3)*32768, h0rL + (g&3)*32768, smem, GI_BASE, bgi, wid, lane, pgi);
      gates_store(pgi, pgh, hold, h1rH + (g&3)*32768, h1rL + (g&3)*32768, colb, wid, lane);
      __syncthreads();
      if (tid == 0) publish(&fB[wg-64], (uint)(g+1));
    }
  } else {
    // ---- FC head: trails B by one handoff
    const int fccol = (wg - 128)*16;
    packFC(smem, p.fcW, fccol, tid);
    bfc = p.fcb[fccol + c];
    __syncthreads();
    for (int t = 0; t < TT; ++t){
      const int g = 512 + t;
      waitge(fB, (uint)(g+1), l);                              // h1^g ready
      f32x4 pre[1];
      gemm<1,512,true>(h1rH + (g&3)*32768, h1rL + (g&3)*32768, smem, 0, &bfc, wid, lane, pre);
      const int outcol = fccol + c, gq = lane >> 4;
#pragma unroll
      for (int q = 0; q < 4; ++q){
        const int row = wid*16 + gq*4 + q;
        p.out[(row*COUT + outcol)*TT + t] = pre[0][q];
      }
      __syncthreads();                                         // all waves' reads of slot done
      if (tid == 0) publish(&fF[wg-128], (uint)(g+1));
    }
  }
}

extern "C" void kernel_launch(void* const* d_in, const int* in_sizes, int n_in,
                              void* d_out, int out_size, void* d_ws, size_t ws_size,
                              hipStream_t stream){
  Params p;
  p.x     = (const float*)d_in[0];  p.f0    = (const float*)d_in[1];
  p.eWih0 = (const float*)d_in[2];  p.eWhh0 = (const float*)d_in[3];
  p.ebih0 = (const float*)d_in[4];  p.ebhh0 = (const float*)d_in[5];
  p.eWih1 = (const float*)d_in[6];  p.eWhh1 = (const float*)d_in[7];
  p.ebih1 = (const float*)d_in[8];  p.ebhh1 = (const float*)d_in[9];
  p.dWih0 = (const float*)d_in[10]; p.dWhh0 = (const float*)d_in[11];
  p.dbih0 = (const float*)d_in[12]; p.dbhh0 = (const float*)d_in[13];
  p.dWih1 = (const float*)d_in[14]; p.dWhh1 = (const float*)d_in[15];
  p.dbih1 = (const float*)d_in[16]; p.dbhh1 = (const float*)d_in[17];
  p.fcW   = (const float*)d_in[18]; p.fcb   = (const float*)d_in[19];
  p.out = (float*)d_out;
  p.ws  = (char*)d_ws;

  hipFuncSetAttribute((const void*)rnn_persist, hipFuncAttributeMaxDynamicSharedMemorySize, SMEM_SIZE);
  hipMemsetAsync(d_ws, 0, WS_BAR_SZ, stream);   // reset all flags each launch
  hipLaunchKernelGGL(rnn_persist, dim3(NWG), dim3(THREADS), SMEM_SIZE, stream, p);
}

// Round 6
// 12817.944 us; speedup vs baseline: 1.8266x; 1.8266x over previous
//
#include <hip/hip_runtime.h>

#define H     512
#define BQ    64
#define TT    512
#define CIN   64
#define COUT  64
#define NWG   132           // 64 stage-A + 64 stage-B + 4 FC
#define THREADS 256
#define RSLOTS 32           // ring slots; address reuse period = 32 steps

typedef unsigned int  uint;
typedef unsigned short ushort;
typedef short bf16x8 __attribute__((ext_vector_type(8)));
typedef float f32x4  __attribute__((ext_vector_type(4)));

// LDS layout (bytes): gate-interleaved weight pair-tiles, bf16 hi+lo
#define GH_BASE   0          // 2 tiles K=512 : 64 KB
#define GI_BASE   65536      // 2 tiles K<=512: 64 KB
#define GI0_BASE  131072     // 2 tiles K=64  :  8 KB  (dec-A t=0 only)
#define SMEM_SIZE 139264

// ws layout (bytes)
#define WS_FLAGS  0          // 132 flags, 64B apart
#define WS_BAR_SZ 16384
#define WS_BP     16384      // b' f32[1536]
#define WS_F0H    22528      // f0 hi bf16[64][64]
#define WS_F0L    30720
#define WS_H0RH   65536      // h0 ring [32][64][512] bf16 hi : 2 MB
#define WS_H0RL   2162688
#define WS_H1RH   4259840
#define WS_H1RL   6356992
#define WS_M      8454144    // M f32[1536][512] (ends ~11.6 MB)

// slot offset in ushorts for absolute step s
#define SLOT(s)   (((s) & (RSLOTS-1)) * 32768)

struct Params {
  const float *x, *f0;
  const float *eWih0,*eWhh0,*ebih0,*ebhh0,*eWih1,*eWhh1,*ebih1,*ebhh1;
  const float *dWih0,*dWhh0,*dbih0,*dbhh0,*dWih1,*dWhh1,*dbih1,*dbhh1;
  const float *fcW,*fcb;
  float* out;
  char* ws;
};

__device__ __forceinline__ ushort f2bf(float v){
  uint b = __float_as_uint(v);
  return (ushort)((b + 0x7FFFu + ((b >> 16) & 1u)) >> 16);
}
__device__ __forceinline__ float bf2f(ushort u){ return __uint_as_float(((uint)u) << 16); }

// ---------------- grid barrier. Flags polled via agent-scope relaxed atomics
// (bypass, always fresh). Ring data read via PLAIN CACHED loads: correctness
// comes from (a) 32-slot no-reuse window and (b) the acquire fence (inv) that
// every wave executes at least once per 16 rounds < reuse window, plus forced
// inv at launch start (cross-replay staleness) and phase transitions.
__device__ __forceinline__ void gbar(uint* flags, uint r, int wg, int tid, bool rel, bool inv){
  __syncthreads();                                   // ring stores drained (vmcnt 0)
  if (tid == 0){
    if (rel) __builtin_amdgcn_fence(__ATOMIC_RELEASE, "agent");   // flush plain-stored staging
    __hip_atomic_store(&flags[wg*16], r, __ATOMIC_RELAXED, __HIP_MEMORY_SCOPE_AGENT);
  }
  asm volatile("" ::: "memory");
  if (tid < NWG){
    uint it = 0;
    while (__hip_atomic_load(&flags[tid*16], __ATOMIC_RELAXED, __HIP_MEMORY_SCOPE_AGENT) < r){
      __builtin_amdgcn_s_sleep(1);
      if ((++it & 63u) == 0u) __builtin_amdgcn_fence(__ATOMIC_ACQUIRE, "agent");  // stale-spin safety only
    }
  }
  __syncthreads();
  if (inv) __builtin_amdgcn_fence(__ATOMIC_ACQUIRE, "agent");     // periodic L1/L2 invalidate
}

// ---------------- pack 2 gate-interleaved pair-tiles (32 slots x K) into LDS
template<int K>
__device__ void packW(char* lds, int base, const float* __restrict__ W, int colbase, int tid){
  for (int e = tid; e < 32*K; e += THREADS){
    int S = e / K, k = e - S*K;
    int gate = S & 3, hcl = S >> 2;
    float v = (gate < 3) ? W[(gate*H + colbase + hcl)*K + k] : 0.f;
    ushort hi = f2bf(v);
    ushort lo = f2bf(v - bf2f(hi));
    int tau = S >> 4, s = S & 15;
    int off = ((s*K + k)*2) ^ ((s & 7) << 4);
    char* tb = lds + base + tau*(16*K*4);
    *(ushort*)(tb + off) = hi;
    *(ushort*)(tb + 16*K*2 + off) = lo;
  }
}

__device__ void packFC(char* lds, const float* __restrict__ fcW, int colbase, int tid){
  for (int e = tid; e < 16*512; e += THREADS){
    int s = e >> 9, k = e & 511;
    float v = fcW[(colbase + s)*512 + k];
    ushort hi = f2bf(v);
    ushort lo = f2bf(v - bf2f(hi));
    int off = ((s*512 + k)*2) ^ ((s & 7) << 4);
    *(ushort*)(lds + off) = hi;
    *(ushort*)(lds + 16*512*2 + off) = lo;
  }
}

__device__ __forceinline__ void loadBias(const float* __restrict__ src, int colbase, int c, float* b){
#pragma unroll
  for (int tau = 0; tau < 2; ++tau){
    int gate = c & 3, hcl = 4*tau + (c >> 2);
    b[tau] = (gate < 3) ? src[gate*H + colbase + hcl] : 0.f;
  }
}

__device__ __forceinline__ void loadHold(const ushort* rh, const ushort* rl, int colb,
                                         int m, int lane, f32x4* hold){
  int c = lane & 15, g = lane >> 4;
#pragma unroll
  for (int tau = 0; tau < 2; ++tau){
    int col = colb + 4*tau + (c >> 2);
#pragma unroll
    for (int q = 0; q < 4; ++q){
      int row = m*16 + g*4 + q;
      hold[tau][q] = bf2f(rh[row*H + col]) + bf2f(rl[row*H + col]);
    }
  }
}

// ---------------- 64xNTAU*16 GEMM tile, split-bf16 3-term, weights from LDS
// A (hi/lo): bf16 [64][K] row-major, PLAIN CACHED loads (L2-shared per XCD),
// all hoisted so the stream pipelines behind one latency.
template<int NTAU, int K>
__device__ __forceinline__ void gemm(const ushort* __restrict__ AH, const ushort* __restrict__ AL,
                                     const char* lds, int base, const float* bias,
                                     int m, int lane, f32x4* pre){
  const int c = lane & 15, g = lane >> 4;
  const int rowoff = (m*16 + c)*K + g*8;
  constexpr int NK = K/32;
  bf16x8 ahv[NK], alv[NK];
#pragma unroll
  for (int kc = 0; kc < NK; ++kc){
    ahv[kc] = *(const bf16x8*)(AH + rowoff + kc*32);
    alv[kc] = *(const bf16x8*)(AL + rowoff + kc*32);
  }
  f32x4 a1[NTAU], a2[NTAU];
#pragma unroll
  for (int tau = 0; tau < NTAU; ++tau){
    a1[tau] = f32x4{bias[tau], bias[tau], bias[tau], bias[tau]};
    a2[tau] = f32x4{0.f, 0.f, 0.f, 0.f};
  }
#pragma unroll
  for (int kc = 0; kc < NK; ++kc){
    const int off = ((c*K + kc*32 + g*8)*2) ^ ((c & 7) << 4);
#pragma unroll
    for (int tau = 0; tau < NTAU; ++tau){
      const char* tb = lds + base + tau*(16*K*4);
      bf16x8 wh = *(const bf16x8*)(tb + off);
      bf16x8 wl = *(const bf16x8*)(tb + 16*K*2 + off);
      a1[tau] = __builtin_amdgcn_mfma_f32_16x16x32_bf16(ahv[kc], wh, a1[tau], 0, 0, 0);
      a2[tau] = __builtin_amdgcn_mfma_f32_16x16x32_bf16(ahv[kc], wl, a2[tau], 0, 0, 0);
      a2[tau] = __builtin_amdgcn_mfma_f32_16x16x32_bf16(alv[kc], wh, a2[tau], 0, 0, 0);
    }
  }
#pragma unroll
  for (int tau = 0; tau < NTAU; ++tau) pre[tau] = a1[tau] + a2[tau];
}

// ---------------- GRU gates + hidden store (write-through relaxed agent atomics:
// fresh at the coherence point before the flag store; consumers' cold-address
// plain loads then fetch fresh lines into their XCD L2.)
__device__ __forceinline__ void gates_store(const f32x4* pgi, const f32x4* pgh, f32x4* hold,
                                            ushort* __restrict__ outH, ushort* __restrict__ outL,
                                            int colb, int m, int lane){
  const int c = lane & 15, g = lane >> 4;
#pragma unroll
  for (int tau = 0; tau < 2; ++tau){
    f32x4 s, n, hn, rsh, zsh;
#pragma unroll
    for (int q = 0; q < 4; ++q) s[q] = 1.f / (1.f + expf(-(pgi[tau][q] + pgh[tau][q])));
#pragma unroll
    for (int q = 0; q < 4; ++q) rsh[q] = __shfl_xor(s[q], 2, 64);
#pragma unroll
    for (int q = 0; q < 4; ++q) zsh[q] = __shfl_xor(s[q], 3, 64);
#pragma unroll
    for (int q = 0; q < 4; ++q) n[q] = tanhf(pgi[tau][q] + rsh[q]*pgh[tau][q]);
#pragma unroll
    for (int q = 0; q < 4; ++q) hn[q] = (1.f - zsh[q])*n[q] + zsh[q]*hold[tau][q];
    hold[tau] = hn;
    if ((c & 3) == 2){
      const int col = colb + 4*tau + (c >> 2);
#pragma unroll
      for (int q = 0; q < 4; ++q){
        const int row = m*16 + g*4 + q;
        ushort hi = f2bf(hn[q]);
        ushort lo = f2bf(hn[q] - bf2f(hi));
        __hip_atomic_store(&outH[row*H + col], hi, __ATOMIC_RELAXED, __HIP_MEMORY_SCOPE_AGENT);
        __hip_atomic_store(&outL[row*H + col], lo, __ATOMIC_RELAXED, __HIP_MEMORY_SCOPE_AGENT);
      }
    }
  }
}

__device__ __forceinline__ f32x4 bc4(float v){ return f32x4{v, v, v, v}; }

__global__ __launch_bounds__(THREADS, 1) void rnn_persist(Params p){
  extern __shared__ char smem[];
  char* ws = p.ws;
  uint* flags = (uint*)(ws + WS_FLAGS);
  float*  bp   = (float*)(ws + WS_BP);
  ushort* f0H  = (ushort*)(ws + WS_F0H);
  ushort* f0L  = (ushort*)(ws + WS_F0L);
  ushort* h0rH = (ushort*)(ws + WS_H0RH);
  ushort* h0rL = (ushort*)(ws + WS_H0RL);
  ushort* h1rH = (ushort*)(ws + WS_H1RH);
  ushort* h1rL = (ushort*)(ws + WS_H1RL);
  float*  Mw   = (float*)(ws + WS_M);
  ushort* xTH  = (ushort*)(void*)p.out;              // staged in d_out; dead before FC writes
  ushort* xTL  = xTH + TT*BQ*CIN;

  const int wg = blockIdx.x, tid = threadIdx.x;
  const int wid = tid >> 6, lane = tid & 63;
  const int c = lane & 15;
  const int gtid = wg*THREADS + tid;
  const int gstride = NWG*THREADS;
  uint bno = 0;

  // ================= prepass: xT (transpose+split), f0, M = dWih0@fcW, b'
  for (int e = gtid; e < TT*BQ*CIN; e += gstride){
    int t = e >> 12, b = (e >> 6) & 63, cc = e & 63;
    float v = p.x[(b*CIN + cc)*TT + t];
    ushort hi = f2bf(v);
    xTH[e] = hi; xTL[e] = f2bf(v - bf2f(hi));
  }
  for (int e = gtid; e < BQ*COUT; e += gstride){
    float v = p.f0[e];
    ushort hi = f2bf(v);
    f0H[e] = hi; f0L[e] = f2bf(v - bf2f(hi));
  }
  {
    const int total = 1536*512;
    const int per = (total + gstride - 1) / gstride;
    const int start = gtid * per;
    for (int i = 0; i < per; ++i){
      int e = start + i;
      if (e >= total) break;
      int rr = e >> 9, q = e & 511;
      float acc = 0.f;
      for (int k = 0; k < 64; ++k) acc += p.dWih0[rr*64 + k] * p.fcW[k*512 + q];
      Mw[e] = acc;
    }
  }
  for (int e = gtid; e < 1536; e += gstride){
    float acc = p.dbih0[e];
    for (int k = 0; k < 64; ++k) acc += p.dWih0[e*64 + k] * p.fcb[k];
    bp[e] = acc;
  }
  gbar(flags, ++bno, wg, tid, true, true);   // release staging + kill cross-replay stale lines

  // ================= pack encoder weights into LDS, load biases
  const bool isA = (wg < 64), isB = (wg >= 64 && wg < 128);
  const int colb = isA ? wg*8 : (wg - 64)*8;
  float bgi[2] = {0.f,0.f}, bgh[2] = {0.f,0.f}, bgi0[2] = {0.f,0.f}, bfc = 0.f;
  f32x4 hold[2]; hold[0] = bc4(0.f); hold[1] = bc4(0.f);
  int fccol = 0;
  if (isA){
    packW<64 >(smem, GI_BASE, p.eWih0, colb, tid);
    packW<512>(smem, GH_BASE, p.eWhh0, colb, tid);
    loadBias(p.ebih0, colb, c, bgi); loadBias(p.ebhh0, colb, c, bgh);
  } else if (isB){
    packW<512>(smem, GI_BASE, p.eWih1, colb, tid);
    packW<512>(smem, GH_BASE, p.eWhh1, colb, tid);
    loadBias(p.ebih1, colb, c, bgi); loadBias(p.ebhh1, colb, c, bgh);
  } else {
    fccol = (wg - 128)*16;
    packFC(smem, p.fcW, fccol, tid);
    bfc = p.fcb[fccol + c];
  }
  gbar(flags, ++bno, wg, tid, false, false);

  // ================= encoder: 513 pipelined rounds (A: L0 @ t=r ; B: L1 @ t=r-1)
  // absolute step numbering: encoder h0/h1 steps 0..511
  for (int r = 0; r <= TT; ++r){
    if (isA && r < TT){
      const int t = r;
      f32x4 pgi[2], pgh[2];
      if (t > 0)
        gemm<2,512>(h0rH + SLOT(t-1), h0rL + SLOT(t-1), smem, GH_BASE, bgh, wid, lane, pgh);
      else { pgh[0] = bc4(bgh[0]); pgh[1] = bc4(bgh[1]); }
      gemm<2,64>(xTH + t*4096, xTL + t*4096, smem, GI_BASE, bgi, wid, lane, pgi);
      gates_store(pgi, pgh, hold, h0rH + SLOT(t), h0rL + SLOT(t), colb, wid, lane);
    } else if (isB && r >= 1){
      const int t = r - 1;
      f32x4 pgi[2], pgh[2];
      if (t > 0)
        gemm<2,512>(h1rH + SLOT(t-1), h1rL + SLOT(t-1), smem, GH_BASE, bgh, wid, lane, pgh);
      else { pgh[0] = bc4(bgh[0]); pgh[1] = bc4(bgh[1]); }
      gemm<2,512>(h0rH + SLOT(t), h0rL + SLOT(t), smem, GI_BASE, bgi, wid, lane, pgi);
      gates_store(pgi, pgh, hold, h1rH + SLOT(t), h1rL + SLOT(t), colb, wid, lane);
    }
    ++bno;
    gbar(flags, bno, wg, tid, false, (bno & 15u) == 0u);
  }

  // ================= repack decoder weights, reload state (enc finals = step 511)
  if (isA){
    packW<512>(smem, GH_BASE, p.dWhh0, colb, tid);
    packW<512>(smem, GI_BASE, Mw,      colb, tid);   // folded FC->L0 input weights
    packW<64 >(smem, GI0_BASE, p.dWih0, colb, tid);
    loadBias(bp,      colb, c, bgi);
    loadBias(p.dbhh0, colb, c, bgh);
    loadBias(p.dbih0, colb, c, bgi0);
    loadHold(h0rH + SLOT(511), h0rL + SLOT(511), colb, wid, lane, hold);
  } else if (isB){
    packW<512>(smem, GI_BASE, p.dWih1, colb, tid);
    packW<512>(smem, GH_BASE, p.dWhh1, colb, tid);
    loadBias(p.dbih1, colb, c, bgi); loadBias(p.dbhh1, colb, c, bgh);
    loadHold(h1rH + SLOT(511), h1rL + SLOT(511), colb, wid, lane, hold);
  }
  gbar(flags, ++bno, wg, tid, false, true);          // phase transition: force inv

  // ================= decoder: 1025 rounds; A fires even r (step g=512+t), B odd.
  // Off-parity rounds precompute the recurrent half (operand one round old).
  f32x4 pgh_s[2]; pgh_s[0] = bc4(0.f); pgh_s[1] = bc4(0.f);
  for (int r = 0; r <= 2*TT; ++r){
    if (isA){
      if (r == 0){
        gemm<2,512>(h0rH + SLOT(511), h0rL + SLOT(511), smem, GH_BASE, bgh, wid, lane, pgh_s);
        f32x4 pgi[2];
        gemm<2,64>(f0H, f0L, smem, GI0_BASE, bgi0, wid, lane, pgi);
        gates_store(pgi, pgh_s, hold, h0rH + SLOT(512), h0rL + SLOT(512), colb, wid, lane);
      } else if (r & 1){
        const int t = (r + 1) >> 1;                  // prefetch gh for next step: h0^{511+t}
        if (t < TT) gemm<2,512>(h0rH + SLOT(511+t), h0rL + SLOT(511+t), smem, GH_BASE, bgh, wid, lane, pgh_s);
      } else {
        const int t = r >> 1;
        if (t < TT){
          f32x4 pgi[2];
          gemm<2,512>(h1rH + SLOT(511+t), h1rL + SLOT(511+t), smem, GI_BASE, bgi, wid, lane, pgi);
          gates_store(pgi, pgh_s, hold, h0rH + SLOT(512+t), h0rL + SLOT(512+t), colb, wid, lane);
        }
      }
    } else if (isB){
      if (!(r & 1)){
        const int t = r >> 1;                        // prefetch gh: h1^{511+t}
        if (t < TT) gemm<2,512>(h1rH + SLOT(511+t), h1rL + SLOT(511+t), smem, GH_BASE, bgh, wid, lane, pgh_s);
      } else {
        const int t = r >> 1;
        f32x4 pgi[2];
        gemm<2,512>(h0rH + SLOT(512+t), h0rL + SLOT(512+t), smem, GI_BASE, bgi, wid, lane, pgi);
        gates_store(pgi, pgh_s, hold, h1rH + SLOT(512+t), h1rL + SLOT(512+t), colb, wid, lane);
      }
    } else {
      if (!(r & 1) && r >= 2){
        const int t = (r - 2) >> 1;                  // FC head, 2 rounds late: h1^{512+t}
        f32x4 pre[1];
        gemm<1,512>(h1rH + SLOT(512+t), h1rL + SLOT(512+t), smem, 0, &bfc, wid, lane, pre);
        const int outcol = fccol + c, gq = lane >> 4;
#pragma unroll
        for (int q = 0; q < 4; ++q){
          const int row = wid*16 + gq*4 + q;
          p.out[(row*COUT + outcol)*TT + t] = pre[0][q];
        }
      }
    }
    ++bno;
    gbar(flags, bno, wg, tid, false, (bno & 15u) == 0u);
  }
}

extern "C" void kernel_launch(void* const* d_in, const int* in_sizes, int n_in,
                              void* d_out, int out_size, void* d_ws, size_t ws_size,
                              hipStream_t stream){
  Params p;
  p.x     = (const float*)d_in[0];  p.f0    = (const float*)d_in[1];
  p.eWih0 = (const float*)d_in[2];  p.eWhh0 = (const float*)d_in[3];
  p.ebih0 = (const float*)d_in[4];  p.ebhh0 = (const float*)d_in[5];
  p.eWih1 = (const float*)d_in[6];  p.eWhh1 = (const float*)d_in[7];
  p.ebih1 = (const float*)d_in[8];  p.ebhh1 = (const float*)d_in[9];
  p.dWih0 = (const float*)d_in[10]; p.dWhh0 = (const float*)d_in[11];
  p.dbih0 = (const float*)d_in[12]; p.dbhh0 = (const float*)d_in[13];
  p.dWih1 = (const float*)d_in[14]; p.dWhh1 = (const float*)d_in[15];
  p.dbih1 = (const float*)d_in[16]; p.dbhh1 = (const float*)d_in[17];
  p.fcW   = (const float*)d_in[18]; p.fcb   = (const float*)d_in[19];
  p.out = (float*)d_out;
  p.ws  = (char*)d_ws;

  hipFuncSetAttribute((const void*)rnn_persist, hipFuncAttributeMaxDynamicSharedMemorySize, SMEM_SIZE);
  hipMemsetAsync(d_ws, 0, WS_BAR_SZ, stream);   // reset barrier flags each launch
  hipLaunchKernelGGL(rnn_persist, dim3(NWG), dim3(THREADS), SMEM_SIZE, stream, p);
}